// Round 5
// baseline (697.072 us; speedup 1.0000x reference)
//
#include <hip/hip_runtime.h>

typedef short short8 __attribute__((ext_vector_type(8)));
typedef float f32x4 __attribute__((ext_vector_type(4)));

__device__ __forceinline__ unsigned short f2b(float f) {
    unsigned u = __float_as_uint(f);
    u += 0x7fffu + ((u >> 16) & 1u);          // round-to-nearest-even
    return (unsigned short)(u >> 16);
}
__device__ __forceinline__ float b2f(unsigned short h) {
    return __uint_as_float(((unsigned)h) << 16);
}

// ---------------------------------------------------------------------------
// 3x3 conv s1, NHWC bf16, mt=2 (32 c_out per wave). Used for conv1 (C_OUT=32).
// Block: 16x16 px x 32 c_out, 4 waves.
// ---------------------------------------------------------------------------
template <int C_IN, int C_OUT, int NW>
__global__ __launch_bounds__(NW * 64) void conv_s1_mfma(
    const unsigned short* __restrict__ in, const unsigned short* __restrict__ wT,
    const float* __restrict__ bias, unsigned short* __restrict__ out,
    int H, int W, int relu)
{
    constexpr int LDSTR  = C_IN + 8;
    constexpr int KSTEPS = C_IN / 32;
    constexpr int CH8    = C_IN / 8;
    constexpr int COPB   = 32 * (NW / 4);
    __shared__ unsigned short s_in[18 * 18 * LDSTR];

    const int tid   = threadIdx.x;
    const int wave  = tid >> 6;
    const int wv    = wave & 3;
    const int csub  = wave >> 2;
    const int lane  = tid & 63;
    const int mlane = lane & 15;
    const int quad  = lane >> 4;

    const int nCo  = C_OUT / COPB;
    const int b    = blockIdx.z / nCo;
    const int coB  = (blockIdx.z - b * nCo) * COPB + csub * 32;
    const int row0 = blockIdx.y * 16;
    const int col0 = blockIdx.x * 16;

    for (int idx = tid; idx < 18 * 18 * CH8; idx += NW * 64) {
        int pixel = idx / CH8;
        int ch    = (idx - pixel * CH8) * 8;
        int pr    = pixel / 18;
        int pc    = pixel - pr * 18;
        int gr = row0 - 1 + pr, gc = col0 - 1 + pc;
        ulonglong2 v; v.x = 0; v.y = 0;
        if ((unsigned)gr < (unsigned)H && (unsigned)gc < (unsigned)W)
            v = *(const ulonglong2*)&in[((b * H + gr) * W + gc) * C_IN + ch];
        *(ulonglong2*)&s_in[pixel * LDSTR + ch] = v;
    }
    __syncthreads();

    f32x4 acc[2][4];
    #pragma unroll
    for (int mt = 0; mt < 2; ++mt)
        #pragma unroll
        for (int t = 0; t < 4; ++t) acc[mt][t] = (f32x4)(0.f);

    #pragma unroll 1
    for (int kk = 0; kk < KSTEPS; ++kk) {
        short8 A[2][9];
        #pragma unroll
        for (int mt = 0; mt < 2; ++mt)
            #pragma unroll
            for (int tap = 0; tap < 9; ++tap)
                A[mt][tap] = *(const short8*)&wT[(tap * C_OUT + coB + mt * 16 + mlane) * C_IN
                                                 + kk * 32 + quad * 8];

        const unsigned short* sb =
            &s_in[(wv * 4 * 18 + mlane) * LDSTR + kk * 32 + quad * 8];
        #pragma unroll
        for (int t = 0; t < 4; ++t) {
            #pragma unroll
            for (int tap = 0; tap < 9; ++tap) {
                const int dy = tap / 3, dx = tap % 3;
                short8 Bf = *(const short8*)&sb[((t + dy) * 18 + dx) * LDSTR];
                acc[0][t] = __builtin_amdgcn_mfma_f32_16x16x32_bf16(A[0][tap], Bf, acc[0][t], 0, 0, 0);
                acc[1][t] = __builtin_amdgcn_mfma_f32_16x16x32_bf16(A[1][tap], Bf, acc[1][t], 0, 0, 0);
            }
        }
    }

    #pragma unroll
    for (int mt = 0; mt < 2; ++mt) {
        const int cb = coB + mt * 16 + quad * 4;
        float4 bv;
        if (bias) bv = *(const float4*)&bias[cb]; else { bv.x = bv.y = bv.z = bv.w = 0.f; }
        #pragma unroll
        for (int t = 0; t < 4; ++t) {
            const int row = row0 + wv * 4 + t, col = col0 + mlane;
            float o0 = acc[mt][t][0] + bv.x, o1 = acc[mt][t][1] + bv.y;
            float o2 = acc[mt][t][2] + bv.z, o3 = acc[mt][t][3] + bv.w;
            if (relu) {
                o0 = fmaxf(o0, 0.f); o1 = fmaxf(o1, 0.f);
                o2 = fmaxf(o2, 0.f); o3 = fmaxf(o3, 0.f);
            }
            ushort4 pk; pk.x = f2b(o0); pk.y = f2b(o1); pk.z = f2b(o2); pk.w = f2b(o3);
            *(ushort4*)&out[((b * H + row) * W + col) * C_OUT + cb] = pk;
        }
    }
}

// ---------------------------------------------------------------------------
// 3x3 conv s1, NHWC bf16, mt=4: each wave = 4 px rows x 16 cols x 64 c_out.
// Tap-outer loop: per tap 4 A-frag loads (L1-hot) + 4 B ds_read_b128 + 16
// MFMA -> MFMA-pipe-bound (698 vs 432 cyc). Block: 16x16 px x 64*(NW/4) co.
// ---------------------------------------------------------------------------
template <int C_IN, int C_OUT, int NW>
__global__ __launch_bounds__(NW * 64) void conv_s1_mt4(
    const unsigned short* __restrict__ in, const unsigned short* __restrict__ wT,
    const float* __restrict__ bias, unsigned short* __restrict__ out,
    int H, int W, int relu)
{
    constexpr int LDSTR  = C_IN + 8;
    constexpr int KSTEPS = C_IN / 32;
    constexpr int CH8    = C_IN / 8;
    constexpr int COPB   = 64 * (NW / 4);
    __shared__ unsigned short s_in[18 * 18 * LDSTR];

    const int tid   = threadIdx.x;
    const int wave  = tid >> 6;
    const int wv    = wave & 3;        // row group
    const int csub  = wave >> 2;       // 64-co sub-block
    const int lane  = tid & 63;
    const int mlane = lane & 15;
    const int quad  = lane >> 4;

    const int nCo  = C_OUT / COPB;
    const int b    = blockIdx.z / nCo;
    const int coB  = (blockIdx.z - b * nCo) * COPB + csub * 64;
    const int row0 = blockIdx.y * 16;
    const int col0 = blockIdx.x * 16;

    for (int idx = tid; idx < 18 * 18 * CH8; idx += NW * 64) {
        int pixel = idx / CH8;
        int ch    = (idx - pixel * CH8) * 8;
        int pr    = pixel / 18;
        int pc    = pixel - pr * 18;
        int gr = row0 - 1 + pr, gc = col0 - 1 + pc;
        ulonglong2 v; v.x = 0; v.y = 0;
        if ((unsigned)gr < (unsigned)H && (unsigned)gc < (unsigned)W)
            v = *(const ulonglong2*)&in[((b * H + gr) * W + gc) * C_IN + ch];
        *(ulonglong2*)&s_in[pixel * LDSTR + ch] = v;
    }
    __syncthreads();

    f32x4 acc[4][4];   // [mt][t]
    #pragma unroll
    for (int mt = 0; mt < 4; ++mt)
        #pragma unroll
        for (int t = 0; t < 4; ++t) acc[mt][t] = (f32x4)(0.f);

    #pragma unroll 1
    for (int kk = 0; kk < KSTEPS; ++kk) {
        const unsigned short* wp = &wT[(coB + mlane) * C_IN + kk * 32 + quad * 8];
        const unsigned short* sb0 = &s_in[(wv * 4 * 18 + mlane) * LDSTR + kk * 32 + quad * 8];
        #pragma unroll
        for (int tap = 0; tap < 9; ++tap) {
            const int dy = tap / 3, dx = tap % 3;
            short8 A[4];
            #pragma unroll
            for (int mt = 0; mt < 4; ++mt)
                A[mt] = *(const short8*)&wp[(tap * C_OUT + mt * 16) * C_IN];
            const unsigned short* sb = &sb0[(dy * 18 + dx) * LDSTR];
            #pragma unroll
            for (int t = 0; t < 4; ++t) {
                short8 Bf = *(const short8*)&sb[t * 18 * LDSTR];
                #pragma unroll
                for (int mt = 0; mt < 4; ++mt)
                    acc[mt][t] = __builtin_amdgcn_mfma_f32_16x16x32_bf16(A[mt], Bf, acc[mt][t], 0, 0, 0);
            }
        }
    }

    #pragma unroll
    for (int mt = 0; mt < 4; ++mt) {
        const int cb = coB + mt * 16 + quad * 4;
        float4 bv;
        if (bias) bv = *(const float4*)&bias[cb]; else { bv.x = bv.y = bv.z = bv.w = 0.f; }
        #pragma unroll
        for (int t = 0; t < 4; ++t) {
            const int row = row0 + wv * 4 + t, col = col0 + mlane;
            float o0 = acc[mt][t][0] + bv.x, o1 = acc[mt][t][1] + bv.y;
            float o2 = acc[mt][t][2] + bv.z, o3 = acc[mt][t][3] + bv.w;
            if (relu) {
                o0 = fmaxf(o0, 0.f); o1 = fmaxf(o1, 0.f);
                o2 = fmaxf(o2, 0.f); o3 = fmaxf(o3, 0.f);
            }
            ushort4 pk; pk.x = f2b(o0); pk.y = f2b(o1); pk.z = f2b(o2); pk.w = f2b(o3);
            *(ushort4*)&out[((b * H + row) * W + col) * C_OUT + cb] = pk;
        }
    }
}

// ---------------------------------------------------------------------------
// 3x3 conv s2, NHWC bf16, MT co-tiles of 16 per wave. Block: 8x8 out px.
// Per tap: MT A-loads + 1 B ds_read + MT MFMA.
// ---------------------------------------------------------------------------
template <int C_IN, int C_OUT, int MT, int NW>
__global__ __launch_bounds__(NW * 64) void conv_s2_mt(
    const unsigned short* __restrict__ in, const unsigned short* __restrict__ wT,
    const float* __restrict__ bias, unsigned short* __restrict__ out,
    int H_in, int W_in, int relu)
{
    constexpr int LDSTR  = C_IN + 8;
    constexpr int KSTEPS = C_IN / 32;
    constexpr int CH8    = C_IN / 8;
    constexpr int COPB   = MT * 16 * (NW / 4);
    __shared__ unsigned short s_in[17 * 17 * LDSTR];

    const int tid   = threadIdx.x;
    const int wave  = tid >> 6;
    const int wv    = wave & 3;
    const int csub  = wave >> 2;
    const int lane  = tid & 63;
    const int mlane = lane & 15;
    const int quad  = lane >> 4;

    const int H_out = H_in >> 1, W_out = W_in >> 1;
    const int nCo   = C_OUT / COPB;
    const int b     = blockIdx.z / nCo;
    const int coB   = (blockIdx.z - b * nCo) * COPB + csub * MT * 16;
    const int orow0 = blockIdx.y * 8, ocol0 = blockIdx.x * 8;
    const int irow0 = orow0 * 2 - 1,  icol0 = ocol0 * 2 - 1;

    for (int idx = tid; idx < 17 * 17 * CH8; idx += NW * 64) {
        int pixel = idx / CH8;
        int ch    = (idx - pixel * CH8) * 8;
        int pr    = pixel / 17;
        int pc    = pixel - pr * 17;
        int gr = irow0 + pr, gc = icol0 + pc;
        ulonglong2 v; v.x = 0; v.y = 0;
        if ((unsigned)gr < (unsigned)H_in && (unsigned)gc < (unsigned)W_in)
            v = *(const ulonglong2*)&in[((b * H_in + gr) * W_in + gc) * C_IN + ch];
        *(ulonglong2*)&s_in[pixel * LDSTR + ch] = v;
    }
    __syncthreads();

    f32x4 acc[MT];
    #pragma unroll
    for (int mt = 0; mt < MT; ++mt) acc[mt] = (f32x4)(0.f);

    const int plr = wv * 2 + (mlane >> 3);
    const int plc = mlane & 7;

    #pragma unroll 1
    for (int kk = 0; kk < KSTEPS; ++kk) {
        const unsigned short* wp = &wT[(coB + mlane) * C_IN + kk * 32 + quad * 8];
        const unsigned short* sb0 =
            &s_in[(plr * 2 * 17 + plc * 2) * LDSTR + kk * 32 + quad * 8];
        #pragma unroll
        for (int tap = 0; tap < 9; ++tap) {
            const int dy = tap / 3, dx = tap % 3;
            short8 A[MT];
            #pragma unroll
            for (int mt = 0; mt < MT; ++mt)
                A[mt] = *(const short8*)&wp[(tap * C_OUT + mt * 16) * C_IN];
            short8 Bf = *(const short8*)&sb0[(dy * 17 + dx) * LDSTR];
            #pragma unroll
            for (int mt = 0; mt < MT; ++mt)
                acc[mt] = __builtin_amdgcn_mfma_f32_16x16x32_bf16(A[mt], Bf, acc[mt], 0, 0, 0);
        }
    }

    const int row = orow0 + plr, col = ocol0 + plc;
    #pragma unroll
    for (int mt = 0; mt < MT; ++mt) {
        const int cb = coB + mt * 16 + quad * 4;
        float4 bv;
        if (bias) bv = *(const float4*)&bias[cb]; else { bv.x = bv.y = bv.z = bv.w = 0.f; }
        float o0 = acc[mt][0] + bv.x, o1 = acc[mt][1] + bv.y;
        float o2 = acc[mt][2] + bv.z, o3 = acc[mt][3] + bv.w;
        if (relu) {
            o0 = fmaxf(o0, 0.f); o1 = fmaxf(o1, 0.f);
            o2 = fmaxf(o2, 0.f); o3 = fmaxf(o3, 0.f);
        }
        ushort4 pk; pk.x = f2b(o0); pk.y = f2b(o1); pk.z = f2b(o2); pk.w = f2b(o3);
        *(ushort4*)&out[((b * H_out + row) * W_out + col) * C_OUT + cb] = pk;
    }
}

// ---------------------------------------------------------------------------
// Paired deformable sampling, NHWC bf16. One block handles the q-tile (first
// image half, offset parity even) AND the q+HW/2 tile (parity odd): they share
// the same physical offset rows m = 2q+j, so the 16KB staged tile is fully
// consumed -> offset HBM traffic halved, 16 outputs/thread.
// ---------------------------------------------------------------------------
template <int LC>
__global__ __launch_bounds__(256) void deform_pair(
    const unsigned short* __restrict__ x, const unsigned short* __restrict__ off,
    unsigned short* __restrict__ out, int lhw, int lw)
{
    constexpr int C   = 1 << LC;
    constexpr int C2  = 2 << LC;
    constexpr int LC2 = LC + 1;
    constexpr int ST  = 256 >> LC;          // pixel stride between u-steps
    __shared__ unsigned short s_off[8192];

    const int HW = 1 << lhw, W = 1 << lw, H = HW >> lw;
    const int tid  = threadIdx.x;
    const int i0c  = blockIdx.x << 11;      // compressed (half-image) index
    const int pix0 = i0c >> LC;
    const int q0   = pix0 & ((HW >> 1) - 1);
    const int b    = pix0 >> (lhw - 1);
    const int ob   = b << lhw;

    // stage rows t = 2q0 .. 2q0 + 2*NPX - 1 (< HW, no wrap), all C2 channels
    const int t0base = q0 << 1;
    #pragma unroll
    for (int j = 0; j < 4; ++j) {
        const int flat = (tid + j * 256) * 8;
        const int r = flat >> LC2;
        const int k = flat & (C2 - 1);
        *(ulonglong2*)&s_off[flat] =
            *(const ulonglong2*)&off[((ob + t0base + r) << LC2) + k];
    }
    __syncthreads();

    const int ci = tid & (C - 1);
    const unsigned short* so = &s_off[(((tid >> LC) << 1) << LC2) + (ci << 1)];
    const unsigned short* xb2 = x + ((long)ob << LC) + ci;
    const int qt = q0 + (tid >> LC);
    const float Hm1 = (float)(H - 1), Wm1 = (float)(W - 1);
    const int dcC = C, drC = C << lw;
    const int H2 = H >> 1;

    float resA[8], resB[8];
    #pragma unroll
    for (int u = 0; u < 8; ++u) {
        const int q = qt + u * ST;
        const int r = q >> lw, c = q & (W - 1);
        const float roA = b2f(so[u * 1024]);
        const float coA = b2f(so[u * 1024 + C2]);
        const float roB = b2f(so[u * 1024 + 1]);
        const float coB = b2f(so[u * 1024 + C2 + 1]);
        {   // first half: pixel q, parity even
            const float rr = fminf(fmaxf(roA + (float)r, 0.f), Hm1);
            const float cc = fminf(fmaxf(coA + (float)c, 0.f), Wm1);
            const float rf = floorf(rr), cf = floorf(cc);
            const float fr = rr - rf,   fc = cc - cf;
            const int idx00 = (((int)rf << lw) + (int)cf) << LC;
            const int dr = (fr > 0.f) ? drC : 0;
            const int dc = (fc > 0.f) ? dcC : 0;
            const float v00 = b2f(xb2[idx00]);
            const float v01 = b2f(xb2[idx00 + dc]);
            const float v10 = b2f(xb2[idx00 + dr]);
            const float v11 = b2f(xb2[idx00 + dr + dc]);
            const float vt = v00 + (v10 - v00) * fr;
            const float vb = v01 + (v11 - v01) * fr;
            resA[u] = vt + (vb - vt) * fc;
        }
        {   // second half: pixel q + HW/2 (row + H/2), parity odd
            const float rr = fminf(fmaxf(roB + (float)(r + H2), 0.f), Hm1);
            const float cc = fminf(fmaxf(coB + (float)c, 0.f), Wm1);
            const float rf = floorf(rr), cf = floorf(cc);
            const float fr = rr - rf,   fc = cc - cf;
            const int idx00 = (((int)rf << lw) + (int)cf) << LC;
            const int dr = (fr > 0.f) ? drC : 0;
            const int dc = (fc > 0.f) ? dcC : 0;
            const float v00 = b2f(xb2[idx00]);
            const float v01 = b2f(xb2[idx00 + dc]);
            const float v10 = b2f(xb2[idx00 + dr]);
            const float v11 = b2f(xb2[idx00 + dr + dc]);
            const float vt = v00 + (v10 - v00) * fr;
            const float vb = v01 + (v11 - v01) * fr;
            resB[u] = vt + (vb - vt) * fc;
        }
    }
    const int baseA = ((ob + q0) << LC) + tid;
    const int halfOff = 1 << (lhw - 1 + LC);
    #pragma unroll
    for (int u = 0; u < 8; ++u) {
        out[baseA + (u << 8)] = f2b(resA[u]);
        out[baseA + halfOff + (u << 8)] = f2b(resB[u]);
    }
}

// ---------------------------------------------------------------------------
// x: fp32 NCHW (C=32) -> bf16 NHWC via LDS transpose. Block: 32ch x 64 px.
// ---------------------------------------------------------------------------
__global__ __launch_bounds__(256) void nchw2nhwc(
    const float* __restrict__ x, unsigned short* __restrict__ out, int HW)
{
    __shared__ float s[32][65];
    const int b = blockIdx.y, p0 = blockIdx.x * 64;
    const int tid = threadIdx.x;
    #pragma unroll
    for (int k = 0; k < 8; ++k) {
        int e = tid + k * 256, ci = e >> 6, p = e & 63;
        s[ci][p] = x[(b * 32 + ci) * HW + p0 + p];
    }
    __syncthreads();
    #pragma unroll
    for (int k = 0; k < 8; ++k) {
        int e = tid + k * 256, p = e >> 5, ci = e & 31;
        out[(b * HW + p0 + p) * 32 + ci] = f2b(s[ci][p]);
    }
}

// all 7 weight transforms in one launch: fp32 OIHW -> bf16 [tap][C_out][C_in]
struct WTArgs {
    const float* src[7];
    unsigned short* dst[7];
    int co[7], ci[7], n[7];
};
__global__ __launch_bounds__(256) void wtrans_all(WTArgs a)
{
    const int i = blockIdx.x * 256 + threadIdx.x;
    #pragma unroll
    for (int s = 0; s < 7; ++s) {
        if (i < a.n[s]) {
            const int ci  = i % a.ci[s];
            const int rr  = i / a.ci[s];
            const int co  = rr % a.co[s];
            const int tap = rr / a.co[s];
            a.dst[s][i] = f2b(a.src[s][(co * a.ci[s] + ci) * 9 + tap]);
        }
    }
}

// global avg pool over 32x32, NHWC bf16 (C=32) -> fp32 (B,C)
__global__ __launch_bounds__(256) void avgpool_nhwc(
    const unsigned short* __restrict__ in, float* __restrict__ out)
{
    const int b = blockIdx.x, tid = threadIdx.x;
    const int ci = tid & 31, pg = tid >> 5;
    float s = 0.f;
    for (int k = 0; k < 128; ++k) {
        int p = pg * 128 + k;
        s += b2f(in[(b * 1024 + p) * 32 + ci]);
    }
    __shared__ float red[8][32];
    red[pg][ci] = s;
    __syncthreads();
    if (tid < 32) {
        float t = 0.f;
        #pragma unroll
        for (int j = 0; j < 8; ++j) t += red[j][tid];
        out[b * 32 + tid] = t * (1.f / 1024.f);
    }
}

__global__ __launch_bounds__(256) void sentinel(float* out, int n, float v)
{
    int i = blockIdx.x * 256 + threadIdx.x;
    if (i < n) out[i] = v;
}

extern "C" void kernel_launch(void* const* d_in, const int* in_sizes, int n_in,
                              void* d_out, int out_size, void* d_ws, size_t ws_size,
                              hipStream_t stream) {
    (void)in_sizes; (void)n_in; (void)out_size;
    const float* x   = (const float*)d_in[0];
    const float* w1  = (const float*)d_in[1];
    const float* b1  = (const float*)d_in[2];
    const float* ow1 = (const float*)d_in[3];
    const float* w2  = (const float*)d_in[4];
    const float* b2  = (const float*)d_in[5];
    const float* ow2 = (const float*)d_in[6];
    const float* w3  = (const float*)d_in[7];
    const float* b3  = (const float*)d_in[8];
    const float* ow3 = (const float*)d_in[9];
    const float* w4  = (const float*)d_in[10];
    const float* b4  = (const float*)d_in[11];
    float* out = (float*)d_out;
    unsigned short* wsu = (unsigned short*)d_ws;

    const size_t XB = 0;
    const size_t HA = 33554432;
    const size_t OB = 67108864;
    const size_t DC = 134217728;
    const size_t WB = 167772160;
    const size_t total_us = WB + 165888;
    if (ws_size < total_us * 2) {
        sentinel<<<2, 256, 0, stream>>>(out, 512, 12345.0f);
        return;
    }
    unsigned short* xb = wsu + XB;
    unsigned short* hA = wsu + HA;
    unsigned short* oB = wsu + OB;
    unsigned short* dC = wsu + DC;
    unsigned short* wt1  = wsu + WB;
    unsigned short* owt1 = wt1 + 9216;
    unsigned short* wt2  = owt1 + 18432;
    unsigned short* owt2 = wt2 + 18432;
    unsigned short* wt3  = owt2 + 73728;
    unsigned short* owt3 = wt3 + 18432;
    unsigned short* wt4  = owt3 + 18432;

    WTArgs wa;
    wa.src[0] = w1;  wa.dst[0] = wt1;  wa.co[0] = 32;  wa.ci[0] = 32; wa.n[0] = 9216;
    wa.src[1] = ow1; wa.dst[1] = owt1; wa.co[1] = 64;  wa.ci[1] = 32; wa.n[1] = 18432;
    wa.src[2] = w2;  wa.dst[2] = wt2;  wa.co[2] = 64;  wa.ci[2] = 32; wa.n[2] = 18432;
    wa.src[3] = ow2; wa.dst[3] = owt2; wa.co[3] = 128; wa.ci[3] = 64; wa.n[3] = 73728;
    wa.src[4] = w3;  wa.dst[4] = wt3;  wa.co[4] = 32;  wa.ci[4] = 64; wa.n[4] = 18432;
    wa.src[5] = ow3; wa.dst[5] = owt3; wa.co[5] = 64;  wa.ci[5] = 32; wa.n[5] = 18432;
    wa.src[6] = w4;  wa.dst[6] = wt4;  wa.co[6] = 32;  wa.ci[6] = 32; wa.n[6] = 9216;
    wtrans_all<<<288, 256, 0, stream>>>(wa);

    nchw2nhwc<<<dim3(1024, 16), 256, 0, stream>>>(x, xb, 65536);

    // L1: conv1 (32->32, 256x256, s1, relu)  mt=2
    conv_s1_mfma<32, 32, 4><<<dim3(16, 16, 16), 256, 0, stream>>>(xb, wt1, b1, hA, 256, 256, 1);
    // offconv1 (32->64)  mt=4
    conv_s1_mt4<32, 64, 4><<<dim3(16, 16, 16), 256, 0, stream>>>(hA, owt1, nullptr, oB, 256, 256, 0);
    deform_pair<5><<<8192, 256, 0, stream>>>(hA, oB, dC, 16, 8);

    // L2: conv2 (32->64, s2) 256->128  mt=4
    conv_s2_mt<32, 64, 4, 4><<<dim3(16, 16, 16), 256, 0, stream>>>(dC, wt2, b2, hA, 256, 256, 1);
    // offconv2 (64->128)  mt=4, 8 waves (2 co-halves per staged tile)
    conv_s1_mt4<64, 128, 8><<<dim3(8, 8, 16), 512, 0, stream>>>(hA, owt2, nullptr, oB, 128, 128, 0);
    deform_pair<6><<<4096, 256, 0, stream>>>(hA, oB, dC, 14, 7);

    // L3: conv3 (64->32, s2) 128->64  mt=2
    conv_s2_mt<64, 32, 2, 4><<<dim3(8, 8, 16), 256, 0, stream>>>(dC, wt3, b3, hA, 128, 128, 1);
    // offconv3 (32->64)  mt=4
    conv_s1_mt4<32, 64, 4><<<dim3(4, 4, 16), 256, 0, stream>>>(hA, owt3, nullptr, oB, 64, 64, 0);
    deform_pair<5><<<512, 256, 0, stream>>>(hA, oB, dC, 12, 6);

    // L4: conv4 (32->32, s2) 64->32  mt=2  (grid x=4: full 32-col coverage)
    conv_s2_mt<32, 32, 2, 4><<<dim3(4, 4, 16), 256, 0, stream>>>(dC, wt4, b4, hA, 64, 64, 1);
    avgpool_nhwc<<<16, 256, 0, stream>>>(hA, out);
}

// Round 6
// 674.310 us; speedup vs baseline: 1.0338x; 1.0338x over previous
//
#include <hip/hip_runtime.h>

typedef short short8 __attribute__((ext_vector_type(8)));
typedef float f32x4 __attribute__((ext_vector_type(4)));

__device__ __forceinline__ unsigned short f2b(float f) {
    unsigned u = __float_as_uint(f);
    u += 0x7fffu + ((u >> 16) & 1u);          // round-to-nearest-even
    return (unsigned short)(u >> 16);
}
__device__ __forceinline__ float b2f(unsigned short h) {
    return __uint_as_float(((unsigned)h) << 16);
}

// ---------------------------------------------------------------------------
// 3x3 conv, pad 1, stride 1, NHWC bf16, bf16 MFMA fp32 accum.
// Block: 16x16 output pixels x (NW/4) co-blocks of 32 c_out. NW waves.
// ---------------------------------------------------------------------------
template <int C_IN, int C_OUT, int NW>
__global__ __launch_bounds__(NW * 64) void conv_s1_mfma(
    const unsigned short* __restrict__ in, const unsigned short* __restrict__ wT,
    const float* __restrict__ bias, unsigned short* __restrict__ out,
    int H, int W, int relu)
{
    constexpr int LDSTR  = C_IN + 8;
    constexpr int KSTEPS = C_IN / 32;
    constexpr int CH8    = C_IN / 8;
    constexpr int COPB   = 32 * (NW / 4);
    __shared__ unsigned short s_in[18 * 18 * LDSTR];

    const int tid   = threadIdx.x;
    const int wave  = tid >> 6;
    const int wv    = wave & 3;
    const int csub  = wave >> 2;
    const int lane  = tid & 63;
    const int mlane = lane & 15;
    const int quad  = lane >> 4;

    const int nCo  = C_OUT / COPB;
    const int b    = blockIdx.z / nCo;
    const int coB  = (blockIdx.z - b * nCo) * COPB + csub * 32;
    const int row0 = blockIdx.y * 16;
    const int col0 = blockIdx.x * 16;

    for (int idx = tid; idx < 18 * 18 * CH8; idx += NW * 64) {
        int pixel = idx / CH8;
        int ch    = (idx - pixel * CH8) * 8;
        int pr    = pixel / 18;
        int pc    = pixel - pr * 18;
        int gr = row0 - 1 + pr, gc = col0 - 1 + pc;
        ulonglong2 v; v.x = 0; v.y = 0;
        if ((unsigned)gr < (unsigned)H && (unsigned)gc < (unsigned)W)
            v = *(const ulonglong2*)&in[((b * H + gr) * W + gc) * C_IN + ch];
        *(ulonglong2*)&s_in[pixel * LDSTR + ch] = v;
    }
    __syncthreads();

    f32x4 acc[2][4];
    #pragma unroll
    for (int mt = 0; mt < 2; ++mt)
        #pragma unroll
        for (int t = 0; t < 4; ++t) acc[mt][t] = (f32x4)(0.f);

    #pragma unroll 1
    for (int kk = 0; kk < KSTEPS; ++kk) {
        short8 A[2][9];
        #pragma unroll
        for (int mt = 0; mt < 2; ++mt)
            #pragma unroll
            for (int tap = 0; tap < 9; ++tap)
                A[mt][tap] = *(const short8*)&wT[(tap * C_OUT + coB + mt * 16 + mlane) * C_IN
                                                 + kk * 32 + quad * 8];

        const unsigned short* sb =
            &s_in[(wv * 4 * 18 + mlane) * LDSTR + kk * 32 + quad * 8];
        #pragma unroll
        for (int t = 0; t < 4; ++t) {
            #pragma unroll
            for (int tap = 0; tap < 9; ++tap) {
                const int dy = tap / 3, dx = tap % 3;
                short8 Bf = *(const short8*)&sb[((t + dy) * 18 + dx) * LDSTR];
                acc[0][t] = __builtin_amdgcn_mfma_f32_16x16x32_bf16(A[0][tap], Bf, acc[0][t], 0, 0, 0);
                acc[1][t] = __builtin_amdgcn_mfma_f32_16x16x32_bf16(A[1][tap], Bf, acc[1][t], 0, 0, 0);
            }
        }
    }

    #pragma unroll
    for (int mt = 0; mt < 2; ++mt) {
        const int cb = coB + mt * 16 + quad * 4;
        float4 bv;
        if (bias) bv = *(const float4*)&bias[cb]; else { bv.x = bv.y = bv.z = bv.w = 0.f; }
        #pragma unroll
        for (int t = 0; t < 4; ++t) {
            const int row = row0 + wv * 4 + t, col = col0 + mlane;
            float o0 = acc[mt][t][0] + bv.x, o1 = acc[mt][t][1] + bv.y;
            float o2 = acc[mt][t][2] + bv.z, o3 = acc[mt][t][3] + bv.w;
            if (relu) {
                o0 = fmaxf(o0, 0.f); o1 = fmaxf(o1, 0.f);
                o2 = fmaxf(o2, 0.f); o3 = fmaxf(o3, 0.f);
            }
            ushort4 pk; pk.x = f2b(o0); pk.y = f2b(o1); pk.z = f2b(o2); pk.w = f2b(o3);
            *(ushort4*)&out[((b * H + row) * W + col) * C_OUT + cb] = pk;
        }
    }
}

// ---------------------------------------------------------------------------
// 3x3 conv, pad 1, stride 2, NHWC bf16. Block: 8x8 out px x (NW/4) co-blocks.
// ---------------------------------------------------------------------------
template <int C_IN, int C_OUT, int NW>
__global__ __launch_bounds__(NW * 64) void conv_s2_mfma(
    const unsigned short* __restrict__ in, const unsigned short* __restrict__ wT,
    const float* __restrict__ bias, unsigned short* __restrict__ out,
    int H_in, int W_in, int relu)
{
    constexpr int LDSTR  = C_IN + 8;
    constexpr int KSTEPS = C_IN / 32;
    constexpr int CH8    = C_IN / 8;
    constexpr int COPB   = 32 * (NW / 4);
    __shared__ unsigned short s_in[17 * 17 * LDSTR];

    const int tid   = threadIdx.x;
    const int wave  = tid >> 6;
    const int wv    = wave & 3;
    const int csub  = wave >> 2;
    const int lane  = tid & 63;
    const int mlane = lane & 15;
    const int quad  = lane >> 4;

    const int H_out = H_in >> 1, W_out = W_in >> 1;
    const int nCo   = C_OUT / COPB;
    const int b     = blockIdx.z / nCo;
    const int coB   = (blockIdx.z - b * nCo) * COPB + csub * 32;
    const int orow0 = blockIdx.y * 8, ocol0 = blockIdx.x * 8;
    const int irow0 = orow0 * 2 - 1,  icol0 = ocol0 * 2 - 1;

    for (int idx = tid; idx < 17 * 17 * CH8; idx += NW * 64) {
        int pixel = idx / CH8;
        int ch    = (idx - pixel * CH8) * 8;
        int pr    = pixel / 17;
        int pc    = pixel - pr * 17;
        int gr = irow0 + pr, gc = icol0 + pc;
        ulonglong2 v; v.x = 0; v.y = 0;
        if ((unsigned)gr < (unsigned)H_in && (unsigned)gc < (unsigned)W_in)
            v = *(const ulonglong2*)&in[((b * H_in + gr) * W_in + gc) * C_IN + ch];
        *(ulonglong2*)&s_in[pixel * LDSTR + ch] = v;
    }
    __syncthreads();

    f32x4 acc[2];
    acc[0] = (f32x4)(0.f); acc[1] = (f32x4)(0.f);

    const int plr = wv * 2 + (mlane >> 3);
    const int plc = mlane & 7;

    #pragma unroll 1
    for (int kk = 0; kk < KSTEPS; ++kk) {
        short8 A[2][9];
        #pragma unroll
        for (int mt = 0; mt < 2; ++mt)
            #pragma unroll
            for (int tap = 0; tap < 9; ++tap)
                A[mt][tap] = *(const short8*)&wT[(tap * C_OUT + coB + mt * 16 + mlane) * C_IN
                                                 + kk * 32 + quad * 8];

        const unsigned short* sb0 =
            &s_in[(plr * 2 * 17 + plc * 2) * LDSTR + kk * 32 + quad * 8];
        #pragma unroll
        for (int tap = 0; tap < 9; ++tap) {
            const int dy = tap / 3, dx = tap % 3;
            short8 Bf = *(const short8*)&sb0[(dy * 17 + dx) * LDSTR];
            acc[0] = __builtin_amdgcn_mfma_f32_16x16x32_bf16(A[0][tap], Bf, acc[0], 0, 0, 0);
            acc[1] = __builtin_amdgcn_mfma_f32_16x16x32_bf16(A[1][tap], Bf, acc[1], 0, 0, 0);
        }
    }

    const int row = orow0 + plr, col = ocol0 + plc;
    #pragma unroll
    for (int mt = 0; mt < 2; ++mt) {
        const int cb = coB + mt * 16 + quad * 4;
        float4 bv;
        if (bias) bv = *(const float4*)&bias[cb]; else { bv.x = bv.y = bv.z = bv.w = 0.f; }
        float o0 = acc[mt][0] + bv.x, o1 = acc[mt][1] + bv.y;
        float o2 = acc[mt][2] + bv.z, o3 = acc[mt][3] + bv.w;
        if (relu) {
            o0 = fmaxf(o0, 0.f); o1 = fmaxf(o1, 0.f);
            o2 = fmaxf(o2, 0.f); o3 = fmaxf(o3, 0.f);
        }
        ushort4 pk; pk.x = f2b(o0); pk.y = f2b(o1); pk.z = f2b(o2); pk.w = f2b(o3);
        *(ushort4*)&out[((b * H_out + row) * W_out + col) * C_OUT + cb] = pk;
    }
}

// ---------------------------------------------------------------------------
// Paired deformable sampling, two-phase. One block = q-tile (parity even) +
// q+HW/2 tile (parity odd), 16 outputs/thread. Phase 1 issues ALL 64 gathers
// into register arrays (~64 loads in flight per wave); phase 2 is pure VALU.
// ---------------------------------------------------------------------------
template <int LC>
__global__ __launch_bounds__(256) void deform_pair(
    const unsigned short* __restrict__ x, const unsigned short* __restrict__ off,
    unsigned short* __restrict__ out, int lhw, int lw)
{
    constexpr int C   = 1 << LC;
    constexpr int C2  = 2 << LC;
    constexpr int LC2 = LC + 1;
    constexpr int ST  = 256 >> LC;          // pixel stride between u-steps
    __shared__ unsigned short s_off[8192];

    const int HW = 1 << lhw, W = 1 << lw, H = HW >> lw;
    const int tid  = threadIdx.x;
    const int i0c  = blockIdx.x << 11;      // compressed (half-image) index
    const int pix0 = i0c >> LC;
    const int q0   = pix0 & ((HW >> 1) - 1);
    const int b    = pix0 >> (lhw - 1);
    const int ob   = b << lhw;

    // stage rows t = 2q0 .. 2q0 + 2*NPX - 1, all C2 channels (16 KB)
    const int t0base = q0 << 1;
    #pragma unroll
    for (int j = 0; j < 4; ++j) {
        const int flat = (tid + j * 256) * 8;
        const int r = flat >> LC2;
        const int k = flat & (C2 - 1);
        *(ulonglong2*)&s_off[flat] =
            *(const ulonglong2*)&off[((ob + t0base + r) << LC2) + k];
    }
    __syncthreads();

    const int ci = tid & (C - 1);
    const unsigned short* so = &s_off[(((tid >> LC) << 1) << LC2) + (ci << 1)];
    const unsigned short* xb2 = x + ((long)ob << LC) + ci;
    const int qt = q0 + (tid >> LC);
    const float Hm1 = (float)(H - 1), Wm1 = (float)(W - 1);
    const int dcC = C, drC = C << lw;
    const int H2 = H >> 1;

    float fr[2][8], fc[2][8];
    unsigned short w00[2][8], w01[2][8], w10[2][8], w11[2][8];

    // phase 1: addresses + issue all gathers
    #pragma unroll
    for (int u = 0; u < 8; ++u) {
        const int q = qt + u * ST;
        const int r = q >> lw, c = q & (W - 1);
        const ushort2 ro = *(const ushort2*)&so[u * 1024];        // (roA, roB)
        const ushort2 co = *(const ushort2*)&so[u * 1024 + C2];   // (coA, coB)
        #pragma unroll
        for (int h = 0; h < 2; ++h) {
            const float rbase = (float)(h ? (r + H2) : r);
            const float rr = fminf(fmaxf(b2f(h ? ro.y : ro.x) + rbase, 0.f), Hm1);
            const float cc = fminf(fmaxf(b2f(h ? co.y : co.x) + (float)c, 0.f), Wm1);
            const float rf = floorf(rr), cf = floorf(cc);
            const float u_fr = rr - rf, u_fc = cc - cf;
            fr[h][u] = u_fr; fc[h][u] = u_fc;
            const int idx00 = (((int)rf << lw) + (int)cf) << LC;
            const int dr = (u_fr > 0.f) ? drC : 0;
            const int dc = (u_fc > 0.f) ? dcC : 0;
            w00[h][u] = xb2[idx00];
            w01[h][u] = xb2[idx00 + dc];
            w10[h][u] = xb2[idx00 + dr];
            w11[h][u] = xb2[idx00 + dr + dc];
        }
    }

    // phase 2: consume
    const int baseA = ((ob + q0) << LC) + tid;
    const int halfOff = 1 << (lhw - 1 + LC);
    #pragma unroll
    for (int u = 0; u < 8; ++u) {
        #pragma unroll
        for (int h = 0; h < 2; ++h) {
            const float v00 = b2f(w00[h][u]), v01 = b2f(w01[h][u]);
            const float v10 = b2f(w10[h][u]), v11 = b2f(w11[h][u]);
            const float vt = v00 + (v10 - v00) * fr[h][u];
            const float vb = v01 + (v11 - v01) * fr[h][u];
            const float rs = vt + (vb - vt) * fc[h][u];
            out[baseA + (h ? halfOff : 0) + (u << 8)] = f2b(rs);
        }
    }
}

// ---------------------------------------------------------------------------
// x: fp32 NCHW (C=32) -> bf16 NHWC via LDS transpose. Block: 32ch x 64 px.
// ---------------------------------------------------------------------------
__global__ __launch_bounds__(256) void nchw2nhwc(
    const float* __restrict__ x, unsigned short* __restrict__ out, int HW)
{
    __shared__ float s[32][65];
    const int b = blockIdx.y, p0 = blockIdx.x * 64;
    const int tid = threadIdx.x;
    #pragma unroll
    for (int k = 0; k < 8; ++k) {
        int e = tid + k * 256, ci = e >> 6, p = e & 63;
        s[ci][p] = x[(b * 32 + ci) * HW + p0 + p];
    }
    __syncthreads();
    #pragma unroll
    for (int k = 0; k < 8; ++k) {
        int e = tid + k * 256, p = e >> 5, ci = e & 31;
        out[(b * HW + p0 + p) * 32 + ci] = f2b(s[ci][p]);
    }
}

// all 7 weight transforms in one launch: fp32 OIHW -> bf16 [tap][C_out][C_in]
struct WTArgs {
    const float* src[7];
    unsigned short* dst[7];
    int co[7], ci[7], n[7];
};
__global__ __launch_bounds__(256) void wtrans_all(WTArgs a)
{
    const int i = blockIdx.x * 256 + threadIdx.x;
    #pragma unroll
    for (int s = 0; s < 7; ++s) {
        if (i < a.n[s]) {
            const int ci  = i % a.ci[s];
            const int rr  = i / a.ci[s];
            const int co  = rr % a.co[s];
            const int tap = rr / a.co[s];
            a.dst[s][i] = f2b(a.src[s][(co * a.ci[s] + ci) * 9 + tap]);
        }
    }
}

// global avg pool over 32x32, NHWC bf16 (C=32) -> fp32 (B,C)
__global__ __launch_bounds__(256) void avgpool_nhwc(
    const unsigned short* __restrict__ in, float* __restrict__ out)
{
    const int b = blockIdx.x, tid = threadIdx.x;
    const int ci = tid & 31, pg = tid >> 5;
    float s = 0.f;
    for (int k = 0; k < 128; ++k) {
        int p = pg * 128 + k;
        s += b2f(in[(b * 1024 + p) * 32 + ci]);
    }
    __shared__ float red[8][32];
    red[pg][ci] = s;
    __syncthreads();
    if (tid < 32) {
        float t = 0.f;
        #pragma unroll
        for (int j = 0; j < 8; ++j) t += red[j][tid];
        out[b * 32 + tid] = t * (1.f / 1024.f);
    }
}

__global__ __launch_bounds__(256) void sentinel(float* out, int n, float v)
{
    int i = blockIdx.x * 256 + threadIdx.x;
    if (i < n) out[i] = v;
}

extern "C" void kernel_launch(void* const* d_in, const int* in_sizes, int n_in,
                              void* d_out, int out_size, void* d_ws, size_t ws_size,
                              hipStream_t stream) {
    (void)in_sizes; (void)n_in; (void)out_size;
    const float* x   = (const float*)d_in[0];
    const float* w1  = (const float*)d_in[1];
    const float* b1  = (const float*)d_in[2];
    const float* ow1 = (const float*)d_in[3];
    const float* w2  = (const float*)d_in[4];
    const float* b2  = (const float*)d_in[5];
    const float* ow2 = (const float*)d_in[6];
    const float* w3  = (const float*)d_in[7];
    const float* b3  = (const float*)d_in[8];
    const float* ow3 = (const float*)d_in[9];
    const float* w4  = (const float*)d_in[10];
    const float* b4  = (const float*)d_in[11];
    float* out = (float*)d_out;
    unsigned short* wsu = (unsigned short*)d_ws;

    const size_t XB = 0;
    const size_t HA = 33554432;
    const size_t OB = 67108864;
    const size_t DC = 134217728;
    const size_t WB = 167772160;
    const size_t total_us = WB + 165888;
    if (ws_size < total_us * 2) {
        sentinel<<<2, 256, 0, stream>>>(out, 512, 12345.0f);
        return;
    }
    unsigned short* xb = wsu + XB;
    unsigned short* hA = wsu + HA;
    unsigned short* oB = wsu + OB;
    unsigned short* dC = wsu + DC;
    unsigned short* wt1  = wsu + WB;
    unsigned short* owt1 = wt1 + 9216;
    unsigned short* wt2  = owt1 + 18432;
    unsigned short* owt2 = wt2 + 18432;
    unsigned short* wt3  = owt2 + 73728;
    unsigned short* owt3 = wt3 + 18432;
    unsigned short* wt4  = owt3 + 18432;

    WTArgs wa;
    wa.src[0] = w1;  wa.dst[0] = wt1;  wa.co[0] = 32;  wa.ci[0] = 32; wa.n[0] = 9216;
    wa.src[1] = ow1; wa.dst[1] = owt1; wa.co[1] = 64;  wa.ci[1] = 32; wa.n[1] = 18432;
    wa.src[2] = w2;  wa.dst[2] = wt2;  wa.co[2] = 64;  wa.ci[2] = 32; wa.n[2] = 18432;
    wa.src[3] = ow2; wa.dst[3] = owt2; wa.co[3] = 128; wa.ci[3] = 64; wa.n[3] = 73728;
    wa.src[4] = w3;  wa.dst[4] = wt3;  wa.co[4] = 32;  wa.ci[4] = 64; wa.n[4] = 18432;
    wa.src[5] = ow3; wa.dst[5] = owt3; wa.co[5] = 64;  wa.ci[5] = 32; wa.n[5] = 18432;
    wa.src[6] = w4;  wa.dst[6] = wt4;  wa.co[6] = 32;  wa.ci[6] = 32; wa.n[6] = 9216;
    wtrans_all<<<288, 256, 0, stream>>>(wa);

    nchw2nhwc<<<dim3(1024, 16), 256, 0, stream>>>(x, xb, 65536);

    // L1: conv1 (32->32, 256x256, s1, relu)
    conv_s1_mfma<32, 32, 4><<<dim3(16, 16, 16), 256, 0, stream>>>(xb, wt1, b1, hA, 256, 256, 1);
    // offconv1 (32->64), 2 co-blocks per staged tile
    conv_s1_mfma<32, 64, 8><<<dim3(16, 16, 16), 512, 0, stream>>>(hA, owt1, nullptr, oB, 256, 256, 0);
    deform_pair<5><<<8192, 256, 0, stream>>>(hA, oB, dC, 16, 8);

    // L2: conv2 (32->64, s2) 256->128
    conv_s2_mfma<32, 64, 8><<<dim3(16, 16, 16), 512, 0, stream>>>(dC, wt2, b2, hA, 256, 256, 1);
    // offconv2 (64->128)
    conv_s1_mfma<64, 128, 8><<<dim3(8, 8, 32), 512, 0, stream>>>(hA, owt2, nullptr, oB, 128, 128, 0);
    deform_pair<6><<<4096, 256, 0, stream>>>(hA, oB, dC, 14, 7);

    // L3: conv3 (64->32, s2) 128->64
    conv_s2_mfma<64, 32, 4><<<dim3(8, 8, 16), 256, 0, stream>>>(dC, wt3, b3, hA, 128, 128, 1);
    // offconv3 (32->64)
    conv_s1_mfma<32, 64, 8><<<dim3(4, 4, 16), 512, 0, stream>>>(hA, owt3, nullptr, oB, 64, 64, 0);
    deform_pair<5><<<512, 256, 0, stream>>>(hA, oB, dC, 12, 6);

    // L4: conv4 (32->32, s2) 64->32
    conv_s2_mfma<32, 32, 4><<<dim3(4, 4, 16), 256, 0, stream>>>(dC, wt4, b4, hA, 64, 64, 1);
    avgpool_nhwc<<<16, 256, 0, stream>>>(hA, out);
}